// Round 1
// baseline (246.660 us; speedup 1.0000x reference)
//
#include <hip/hip_runtime.h>
#include <math.h>
#include <stdint.h>

#define NLEV 16
#define TBL 524288
#define TMASK (TBL - 1)
#define BLOCK 256

struct ResArr { float r[NLEV]; };

__device__ __forceinline__ float silu_f(float v) {
    // x * sigmoid(x); fast exp + fast divide, ~2 ulp (threshold is 2% rel)
    return __fdividef(v, 1.0f + __expf(-v));
}

__global__ void __launch_bounds__(BLOCK)
hashgrid_mlp_kernel(const float* __restrict__ x,
                    const float* __restrict__ emb,
                    const float* __restrict__ W1,
                    const float* __restrict__ b1,
                    const float* __restrict__ W2,
                    const float* __restrict__ b2,
                    const float* __restrict__ Wout,
                    const float* __restrict__ bout,
                    float* __restrict__ out,
                    ResArr res)
{
    __shared__ float sx[BLOCK * 3];
    const int t = threadIdx.x;
    const int base = blockIdx.x * BLOCK;

    // coalesced stage of this block's 256 samples (768 floats)
    const float* xblk = x + (size_t)base * 3;
    #pragma unroll
    for (int i = 0; i < 3; ++i) sx[t + i * BLOCK] = xblk[t + i * BLOCK];
    __syncthreads();

    const float xn0 = (sx[t * 3 + 0] + 1.0f) * 0.5f;
    const float xn1 = (sx[t * 3 + 1] + 1.0f) * 0.5f;
    const float xn2 = (sx[t * 3 + 2] + 1.0f) * 0.5f;

    float enc[2 * NLEV];

    #pragma unroll
    for (int l = 0; l < NLEV; ++l) {
        const float rs = res.r[l];
        const float g0 = xn0 * rs, g1 = xn1 * rs, g2 = xn2 * rs;
        const float f0 = floorf(g0), f1 = floorf(g1), f2 = floorf(g2);
        const float w0 = g0 - f0, w1 = g1 - f1, w2 = g2 - f2;
        const uint32_t u0 = (uint32_t)f0, u1 = (uint32_t)f1, u2 = (uint32_t)f2;
        // base hash: dim0*1 + dim1*P1 + dim2*P2 (uint32 wraparound == reference)
        const uint32_t hb = u0 + u1 * 2654435761u + u2 * 805459861u;
        const float2* tab = (const float2*)emb + (size_t)l * TBL;

        const float om0 = 1.0f - w0, om1 = 1.0f - w1, om2 = 1.0f - w2;
        float e0 = 0.0f, e1 = 0.0f;
        #pragma unroll
        for (int c = 0; c < 8; ++c) {
            // MSB-first corner bits: b0->dim0, b1->dim1, b2->dim2
            const uint32_t cb0 = (c >> 2) & 1, cb1 = (c >> 1) & 1, cb2 = c & 1;
            uint32_t h = hb;
            if (cb0) h += 1u;
            if (cb1) h += 2654435761u;
            if (cb2) h += 805459861u;
            h &= TMASK;
            const float2 v = tab[h];
            float wt = (cb0 ? w0 : om0) * (cb1 ? w1 : om1);
            wt *= (cb2 ? w2 : om2);
            e0 = fmaf(wt, v.x, e0);
            e1 = fmaf(wt, v.y, e1);
        }
        enc[2 * l + 0] = e0;
        enc[2 * l + 1] = e1;
    }

    // ---- MLP: 32 -> 64 (silu) -> 64 (silu) -> 1 ----
    // Weight indices are compile-time constants => wave-uniform => s_load path.
    float h1[64];
    #pragma unroll
    for (int i = 0; i < 64; ++i) {
        float acc = b1[i];
        #pragma unroll
        for (int k = 0; k < 32; ++k)
            acc = fmaf(enc[k], W1[i * 32 + k], acc);
        h1[i] = silu_f(acc);
    }

    float o = bout[0];
    #pragma unroll
    for (int i = 0; i < 64; ++i) {
        float acc = b2[i];
        #pragma unroll
        for (int k = 0; k < 64; ++k)
            acc = fmaf(h1[k], W2[i * 64 + k], acc);
        o = fmaf(silu_f(acc), Wout[i], o);
    }

    out[base + t] = o;
}

extern "C" void kernel_launch(void* const* d_in, const int* in_sizes, int n_in,
                              void* d_out, int out_size, void* d_ws, size_t ws_size,
                              hipStream_t stream) {
    const float* x    = (const float*)d_in[0];
    const float* emb  = (const float*)d_in[1];
    const float* W1   = (const float*)d_in[2];
    const float* b1   = (const float*)d_in[3];
    const float* W2   = (const float*)d_in[4];
    const float* b2   = (const float*)d_in[5];
    const float* Wout = (const float*)d_in[6];
    const float* bout = (const float*)d_in[7];
    float* out = (float*)d_out;

    ResArr res;
    const double lg0 = log(16.0), lg1 = log(2048.0);
    for (int i = 0; i < NLEV; ++i)
        res.r[i] = (float)exp(lg0 + (lg1 - lg0) * (double)i / 15.0);

    const int n = in_sizes[0] / 3;            // 262144 samples
    dim3 grid(n / BLOCK);
    hashgrid_mlp_kernel<<<grid, BLOCK, 0, stream>>>(x, emb, W1, b1, W2, b2,
                                                    Wout, bout, out, res);
}